// Round 11
// baseline (232.723 us; speedup 1.0000x reference)
//
#include <hip/hip_runtime.h>

// Quantizer_fp4: out = (code[argmin|x/scale + zero - code|] - zero) * scale
// x: [4096, 8192] f32, scale/zero: [4096, 1] f32, out: [4096, 8192] f32.
// codebook (post +4): {0, 2, 3, 4, 4, 5, 6, 8}; first-index-wins ties.
//
// Evidence ledger (absmax): CR-f32 (R2,R5) = 0.4648438; full-f64 (R6) =
// 0.4648438; hw-rcp+mul+add pinned (R7) = 0.4648438. Each would be ~0 on
// bit-match -> ref is a 1-ulp-class f32 divide, neither CR-div nor raw rcp.
// Probe P1: the reciprocal-multiply rewrite q = x * fl32_CR(1/s) + z
// (XLA algebraic simplifier form for broadcast divisors: one CR reciprocal
// per row, CR mul, separate CR add). P2 fallback: LLVM 2.5-ulp fdiv
// expansion (rcp + NR on reciprocal and quotient).

#define COLS_SHIFT 13               // log2(8192)
#define VEC_SHIFT (COLS_SHIFT - 2)  // float4 index -> row shift

// Correctly-rounded fl32(1/d), flag-immune: f32 hw-rcp seed + f64 Newton
// with explicit __builtin_fma. Error ~2^-52 rel << 2^-49 hard-case margin
// -> fl32 of it is the CR f32 reciprocal.
__device__ __forceinline__ float recip_rn32(float d) {
    double dd = (double)d;
    double r = (double)__builtin_amdgcn_rcpf(d);
    r = __builtin_fma(__builtin_fma(-dd, r, 1.0), r, r);
    r = __builtin_fma(__builtin_fma(-dd, r, 1.0), r, r);
    return (float)r;
}

__device__ __forceinline__ float quant1(float xv, float r, float s, float z) {
    float m = xv * r;
    asm volatile("" : "+v"(m));      // pin: no fma(x, r, z) contraction
    float q = m + z;
    asm volatile("" : "+v"(q));      // pin: no reassociation past here
    const float codes[8] = {0.f, 2.f, 3.f, 4.f, 4.f, 5.f, 6.f, 8.f};
    float best = fabsf(q - codes[0]);
    float qv = codes[0];
#pragma unroll
    for (int k = 1; k < 8; ++k) {
        float d = fabsf(q - codes[k]);
        if (d < best) { best = d; qv = codes[k]; }  // strict <: first wins
    }
    return (qv - z) * s;             // (qv-z) integer-exact; single CR mul
}

__global__ __launch_bounds__(256) void fp4_quant_kernel(
        const float* __restrict__ x, const float* __restrict__ scale,
        const float* __restrict__ zero, float* __restrict__ out, int nvec) {
    const int stride = gridDim.x * blockDim.x;
    for (int i = blockIdx.x * blockDim.x + threadIdx.x; i < nvec; i += stride) {
        const float4 xv = reinterpret_cast<const float4*>(x)[i];
        const int row = i >> VEC_SHIFT;     // all 4 elems share one row
        const float s = scale[row];
        const float z = zero[row];
        const float r = recip_rn32(s);      // CR f32 reciprocal, once per iter
        float4 ov;
        ov.x = quant1(xv.x, r, s, z);
        ov.y = quant1(xv.y, r, s, z);
        ov.z = quant1(xv.z, r, s, z);
        ov.w = quant1(xv.w, r, s, z);
        reinterpret_cast<float4*>(out)[i] = ov;
    }
}

extern "C" void kernel_launch(void* const* d_in, const int* in_sizes, int n_in,
                              void* d_out, int out_size, void* d_ws, size_t ws_size,
                              hipStream_t stream) {
    const float* x     = (const float*)d_in[0];
    const float* scale = (const float*)d_in[1];
    const float* zero  = (const float*)d_in[2];
    float* out = (float*)d_out;

    const int n = in_sizes[0];          // 4096*8192
    const int nvec = n / 4;             // float4 count
    const int block = 256;
    int grid = (nvec + block - 1) / block;
    if (grid > 2048) grid = 2048;       // memory-bound: grid-stride the rest

    fp4_quant_kernel<<<grid, block, 0, stream>>>(x, scale, zero, out, nvec);
}